// Round 1
// baseline (361.004 us; speedup 1.0000x reference)
//
#include <hip/hip_runtime.h>
#include <stdint.h>

typedef unsigned short u16;
typedef __bf16 bf16x8 __attribute__((ext_vector_type(8)));
typedef float f32x4 __attribute__((ext_vector_type(4)));
typedef u16 u16x4 __attribute__((ext_vector_type(4)));

#define MFMA16(a, b, c) __builtin_amdgcn_mfma_f32_16x16x32_bf16((a), (b), (c), 0, 0, 0)

__device__ __forceinline__ u16 f2bf(float f) {
  uint32_t u = __builtin_bit_cast(uint32_t, f);
  u += 0x7FFFu + ((u >> 16) & 1u);  // RNE
  return (u16)(u >> 16);
}
__device__ __forceinline__ bf16x8 cvt8(f32x4 lo, f32x4 hi) {
  union { u16 u[8]; bf16x8 v; } r;
#pragma unroll
  for (int j = 0; j < 4; j++) { r.u[j] = f2bf(lo[j]); r.u[4 + j] = f2bf(hi[j]); }
  return r.v;
}
// async global->LDS, 16B per lane. LDS dest = wave-uniform base + lane*16.
__device__ __forceinline__ void gld_lds16(const void* g, void* l) {
  __builtin_amdgcn_global_load_lds(
      (const __attribute__((address_space(1))) uint32_t*)g,
      (__attribute__((address_space(3))) uint32_t*)l, 16, 0, 0);
}

// ---------------------------------------------------------------------------
// Fused prep: blocks [0,65536) spline-interp the 4 weight curves (n=32539
// f32 cps -> 4.2M bf16 samples each); blocks [65536,69632) convert x f32->bf16.
// ---------------------------------------------------------------------------
__global__ void prep_kernel(const float* __restrict__ x, const float* __restrict__ cpq,
                            const float* __restrict__ cpk, const float* __restrict__ cpv,
                            const float* __restrict__ cpo, u16* __restrict__ xb,
                            u16* __restrict__ Wqkv, u16* __restrict__ Wo,
                            int n, double factor) {
  int blk = blockIdx.x;
  if (blk < 65536) {
    int idx = blk * 256 + threadIdx.x;           // < 4*4194304
    int w = idx >> 22;
    int i = idx & 4194303;
    const float* cp = (w == 0) ? cpq : (w == 1) ? cpk : (w == 2) ? cpv : cpo;
    double u = (double)i * factor;               // f64: f32 too coarse here
    int i0 = (int)u;
    if (i0 > n - 2) i0 = n - 2;
    float fr = (float)(u - (double)i0);
    float f0 = cp[i0], f1 = cp[i0 + 1];
    u16 bv = f2bf(f0 + fr * (f1 - f0));
    if (w < 3) Wqkv[idx] = bv; else Wo[i] = bv;
  } else {
    size_t i = ((size_t)(blk - 65536) * 256 + threadIdx.x) * 8;
    const f32x4* p = (const f32x4*)(x + i);
    *(bf16x8*)(xb + i) = cvt8(p[0], p[1]);
  }
}

// ---------------------------------------------------------------------------
// NEW: QKV projection GEMM with counted-vmcnt pipeline (T3+T4) + setprio (T5).
// C[M=4096, N=6144] = A[M,2048] @ B[N,2048]^T, bf16 in, f32 acc.
// BM=256 x BN=128 x BK=32, 512 threads (8 waves, 4m x 2n, 64x64/wave),
// LDS triple-buffered (72 KiB -> 2 blocks/CU target), grid 768 = 3x256 CUs.
// Schedule per K-tile t:  stage(t+2 -> buf[(t+2)%3]) ; ds_read 8 x b128 from
// buf[t%3] ; 16 MFMA (setprio 1) ; s_waitcnt vmcnt(3)  [t+1 done, t+2 in
// flight -- never drained to 0 in steady state] ; raw s_barrier.
// XOR chunk swizzle applied to BOTH the stage global source and the ds_read
// address (same involution); global_load_lds dest stays linear.
// Epilogue: BN=128 => each block owns exactly one (Q|K|V, head) pair.
// ---------------------------------------------------------------------------
__global__ __launch_bounds__(512, 4)
void gemm_qkv(const u16* __restrict__ A, const u16* __restrict__ B,
              u16* __restrict__ oQ, u16* __restrict__ oK, u16* __restrict__ oV) {
  constexpr int KD = 2048;
  constexpr int NT = KD / 32;  // 64 k-tiles
  __shared__ __align__(16) u16 As[3 * 256 * 32];   // 49152 B
  __shared__ __align__(16) u16 Bs[3 * 128 * 32];   // 24576 B
  const int tid = threadIdx.x;
  const int wave = tid >> 6, lane = tid & 63, quad = lane >> 4, l16 = lane & 15;
  const int wm = wave >> 1, wn = wave & 1;
  // supertile decode: 768 blocks = 3 supertiles x (16m x 16n); one supertile's
  // working set = 16MB A + 8MB B ~= aggregate L2.
  const int z = blockIdx.x;
  const int mt = (z >> 4) & 15;
  const int nt = ((z >> 8) << 4) | (z & 15);
  const int m0 = mt * 256, n0 = nt * 128;

  // staging slots: A = 1024 16B-chunks (2/thread), B = 512 (1/thread)
  const int sA0 = wave * 128 + lane;
  const int sA1 = sA0 + 64;
  const int sB = wave * 64 + lane;
  auto mkoff = [&](int s, int rbase) -> size_t {   // inverse-swizzled global src
    int r = s >> 2, c = s & 3;
    int gc = c ^ ((r ^ (r >> 2)) & 3);
    return (size_t)(rbase + r) * (KD * 2) + gc * 16;
  };
  const size_t aoff0 = mkoff(sA0, m0);
  const size_t aoff1 = mkoff(sA1, m0);
  const size_t boff = mkoff(sB, n0);
  const int lA0 = sA0 * 16, lA1 = sA1 * 16, lB = sB * 16;

  // ds_read byte offsets (swizzled; constant per thread)
  int roffA[4], roffB[4];
#pragma unroll
  for (int mi = 0; mi < 4; mi++) {
    int row = wm * 64 + mi * 16 + l16;
    roffA[mi] = row * 64 + ((quad ^ ((row ^ (row >> 2)) & 3)) * 16);
  }
#pragma unroll
  for (int nj = 0; nj < 4; nj++) {
    int row = wn * 64 + nj * 16 + l16;
    roffB[nj] = row * 64 + ((quad ^ ((row ^ (row >> 2)) & 3)) * 16);
  }

  const char* Ab = (const char*)A;
  const char* Bb = (const char*)B;
  char* AsB = (char*)As;
  char* BsB = (char*)Bs;

  f32x4 acc[4][4];
  const f32x4 fz = {0.f, 0.f, 0.f, 0.f};
#pragma unroll
  for (int i = 0; i < 4; i++)
#pragma unroll
    for (int j = 0; j < 4; j++) acc[i][j] = fz;

  auto STAGE = [&](int ba, int bb, size_t kb) {  // 3 loads/thread
    gld_lds16(Ab + aoff0 + kb, AsB + ba + lA0);
    gld_lds16(Ab + aoff1 + kb, AsB + ba + lA1);
    gld_lds16(Bb + boff + kb, BsB + bb + lB);
  };

#define QKV_BODY(T, CUR, NX2)                                                 \
  do {                                                                        \
    if ((T) + 2 < NT)                                                         \
      STAGE((NX2) * 16384, (NX2) * 8192, (size_t)((T) + 2) * 64);             \
    bf16x8 af[4], bfv[4];                                                     \
    _Pragma("unroll") for (int mi = 0; mi < 4; mi++)                          \
        af[mi] = *(const bf16x8*)(AsB + (CUR) * 16384 + roffA[mi]);           \
    _Pragma("unroll") for (int nj = 0; nj < 4; nj++)                          \
        bfv[nj] = *(const bf16x8*)(BsB + (CUR) * 8192 + roffB[nj]);           \
    __builtin_amdgcn_s_setprio(1);                                            \
    _Pragma("unroll") for (int mi = 0; mi < 4; mi++)                          \
        _Pragma("unroll") for (int nj = 0; nj < 4; nj++)                      \
            acc[mi][nj] = MFMA16(af[mi], bfv[nj], acc[mi][nj]);               \
    __builtin_amdgcn_s_setprio(0);                                            \
    if ((T) + 2 < NT)                                                         \
      asm volatile("s_waitcnt vmcnt(3)" ::: "memory");                        \
    else if ((T) + 1 < NT)                                                    \
      asm volatile("s_waitcnt vmcnt(0)" ::: "memory");                        \
    if ((T) + 1 < NT) {                                                       \
      __builtin_amdgcn_s_barrier();                                           \
      __builtin_amdgcn_sched_barrier(0);                                      \
    }                                                                         \
  } while (0)

  // prologue: tiles 0,1 -> buf 0,1; wait tile0 (3 of 6 outstanding remain)
  STAGE(0, 0, 0);
  STAGE(16384, 8192, 64);
  asm volatile("s_waitcnt vmcnt(3)" ::: "memory");
  __builtin_amdgcn_s_barrier();
  __builtin_amdgcn_sched_barrier(0);

  for (int t = 0; t < 63; t += 3) {
    QKV_BODY(t, 0, 2);
    QKV_BODY(t + 1, 1, 0);
    QKV_BODY(t + 2, 2, 1);
  }
  QKV_BODY(63, 0, 2);
#undef QKV_BODY

  // epilogue: C frag layout col=lane&15 (n), row=quad*4+reg (m).
  // n0 is 128-aligned -> (sel, h) block-uniform.
  const int sel = n0 >> 11;
  const int h = (n0 >> 7) & 15;
  const int bq = m0 >> 11;
  const int sb2 = m0 & 2047;
  if (sel == 2) {  // V -> Vt[B,H,D,S], pack 4 consecutive s
#pragma unroll
    for (int nj = 0; nj < 4; nj++) {
      int d = wn * 64 + nj * 16 + l16;
      size_t colb = ((size_t)((bq << 4) + h) * 128 + d) * 2048;
#pragma unroll
      for (int mi = 0; mi < 4; mi++) {
        int srow = sb2 + wm * 64 + mi * 16 + quad * 4;
        u16x4 pk = {f2bf(acc[mi][nj][0]), f2bf(acc[mi][nj][1]),
                    f2bf(acc[mi][nj][2]), f2bf(acc[mi][nj][3])};
        *(u16x4*)&oV[colb + srow] = pk;
      }
    }
  } else {  // Q (pre-scaled) or K -> [B,H,S,D]
    u16* __restrict__ o = (sel == 0) ? oQ : oK;
    const float sc = (sel == 0) ? 0.08838834764831845f : 1.0f;
    const int base = ((bq << 4) + h) * 2048;
#pragma unroll
    for (int nj = 0; nj < 4; nj++) {
      int d = wn * 64 + nj * 16 + l16;
#pragma unroll
      for (int mi = 0; mi < 4; mi++) {
        int srow = sb2 + wm * 64 + mi * 16 + quad * 4;
#pragma unroll
        for (int r = 0; r < 4; r++)
          o[(size_t)(base + srow + r) * 128 + d] = f2bf(acc[mi][nj][r] * sc);
      }
    }
  }
}

// ---------------------------------------------------------------------------
// C[M,N] = A[M,2048] @ B[N,2048]^T, bf16 in, f32 acc. 128x128 tile, BK=64.
// Retained (proven) for the output projection only (MODE 1).
// ---------------------------------------------------------------------------
template <int MODE>
__global__ __launch_bounds__(256, 2)
void gemm_bt(const u16* __restrict__ A, const u16* __restrict__ B,
             u16* __restrict__ oQ, u16* __restrict__ oK, u16* __restrict__ oV,
             float* __restrict__ oC) {
  constexpr int KD = 2048;
  __shared__ __align__(16) u16 As[128 * 64];
  __shared__ __align__(16) u16 Bs[128 * 64];
  const int tid = threadIdx.x;
  const int wave = tid >> 6, lane = tid & 63, quad = lane >> 4, l16 = lane & 15;
  const int wm = wave & 1, wn = wave >> 1;
  const int m0 = blockIdx.y * 128, n0 = blockIdx.x * 128;

  size_t aoff[4], boff[4];
  int lslot[4];
#pragma unroll
  for (int b = 0; b < 4; b++) {
    int s = wave * 256 + b * 64 + lane;  // chunk slot 0..1023 (16B chunks)
    int r = s >> 3, c = s & 7, gc = c ^ (r & 7);
    lslot[b] = s * 16;
    aoff[b] = (size_t)(m0 + r) * (KD * 2) + gc * 16;
    boff[b] = (size_t)(n0 + r) * (KD * 2) + gc * 16;
  }
  const char* Ab = (const char*)A;
  const char* Bb = (const char*)B;
  char* AsB = (char*)As;
  char* BsB = (char*)Bs;

  f32x4 acc[4][4];
  const f32x4 fz = {0.f, 0.f, 0.f, 0.f};
#pragma unroll
  for (int i = 0; i < 4; i++)
#pragma unroll
    for (int j = 0; j < 4; j++) acc[i][j] = fz;

  for (int kt = 0; kt < KD / 64; ++kt) {
    if (kt) __syncthreads();
#pragma unroll
    for (int b = 0; b < 4; b++) {
      gld_lds16(Ab + aoff[b], AsB + lslot[b]);
      gld_lds16(Bb + boff[b], BsB + lslot[b]);
      aoff[b] += 128;
      boff[b] += 128;
    }
    __syncthreads();
#pragma unroll
    for (int t = 0; t < 2; t++) {
      bf16x8 af[4], bfb[4];
#pragma unroll
      for (int i = 0; i < 4; i++) {
        int row = wm * 64 + i * 16 + l16;
        int ch = (t * 4 + quad) ^ (row & 7);
        af[i] = *(const bf16x8*)(AsB + row * 128 + ch * 16);
      }
#pragma unroll
      for (int j = 0; j < 4; j++) {
        int row = wn * 64 + j * 16 + l16;
        int ch = (t * 4 + quad) ^ (row & 7);
        bfb[j] = *(const bf16x8*)(BsB + row * 128 + ch * 16);
      }
#pragma unroll
      for (int i = 0; i < 4; i++)
#pragma unroll
        for (int j = 0; j < 4; j++) acc[i][j] = MFMA16(af[i], bfb[j], acc[i][j]);
    }
  }

  if (MODE == 0) {
    const float qscale = 0.08838834764831845f;  // folded into Q
#pragma unroll
    for (int j = 0; j < 4; j++) {
      int nb = n0 + wn * 64 + j * 16;
      int sel = nb >> 11;
      int h = (nb >> 7) & 15;
      int d = (nb & 127) + l16;
#pragma unroll
      for (int i = 0; i < 4; i++) {
        int mrow = m0 + wm * 64 + i * 16 + quad * 4;
        int bq = mrow >> 11, srow = mrow & 2047;
        if (sel == 2) {
          u16x4 pk = {f2bf(acc[i][j][0]), f2bf(acc[i][j][1]),
                      f2bf(acc[i][j][2]), f2bf(acc[i][j][3])};
          *(u16x4*)&oV[(size_t)(((bq << 4) + h) * 128 + d) * 2048 + srow] = pk;
        } else if (sel == 0) {
          int base = ((bq << 4) + h) * 2048;
#pragma unroll
          for (int r = 0; r < 4; r++)
            oQ[(size_t)(base + srow + r) * 128 + d] = f2bf(acc[i][j][r] * qscale);
        } else {
          int base = ((bq << 4) + h) * 2048;
#pragma unroll
          for (int r = 0; r < 4; r++)
            oK[(size_t)(base + srow + r) * 128 + d] = f2bf(acc[i][j][r]);
        }
      }
    }
  } else {
#pragma unroll
    for (int j = 0; j < 4; j++) {
      int col = n0 + wn * 64 + j * 16 + l16;
#pragma unroll
      for (int i = 0; i < 4; i++) {
        int mrow = m0 + wm * 64 + i * 16 + quad * 4;
#pragma unroll
        for (int r = 0; r < 4; r++) oC[(size_t)(mrow + r) * 2048 + col] = acc[i][j][r];
      }
    }
  }
}

// ---------------------------------------------------------------------------
// Causal flash attention, Bc=64, max-free softmax, TRANSPOSED QK (unchanged).
// ---------------------------------------------------------------------------
__global__ __launch_bounds__(256, 2)
void flash_attn(const u16* __restrict__ Q, const u16* __restrict__ Kg,
                const u16* __restrict__ Vt, u16* __restrict__ attn) {
  __shared__ __align__(16) u16 Ks[64 * 128];
  __shared__ __align__(16) u16 Vs[128 * 64];
  __shared__ __align__(16) u16 Ps[128 * 72];
  const int tid = threadIdx.x;
  const int wave = tid >> 6, lane = tid & 63, quad = lane >> 4, l16 = lane & 15;
  const int L = blockIdx.x;
  const int bh = L & 31;
  const int qi = (L >> 5) & 7;
  const int qt = (L >= 256) ? (15 - qi) : qi;
  const int q0 = qt * 128;
  const u16* Qb = Q + (size_t)bh * 2048 * 128;
  const u16* Kb = Kg + (size_t)bh * 2048 * 128;
  const u16* Vb = Vt + (size_t)bh * 128 * 2048;

  bf16x8 qf[2][4];
#pragma unroll
  for (int i = 0; i < 2; i++) {
    int row = q0 + wave * 32 + i * 16 + l16;
#pragma unroll
    for (int t = 0; t < 4; t++)
      qf[i][t] = *(const bf16x8*)(Qb + (size_t)row * 128 + t * 32 + quad * 8);
  }

  f32x4 o_acc[2][8];
  const f32x4 fz = {0.f, 0.f, 0.f, 0.f};
#pragma unroll
  for (int i = 0; i < 2; i++)
#pragma unroll
    for (int j = 0; j < 8; j++) o_acc[i][j] = fz;
  float l_i[2] = {0.f, 0.f};

  int koff[4], voff[4], lslot[4];
#pragma unroll
  for (int b = 0; b < 4; b++) {
    int s = wave * 256 + b * 64 + lane;  // 0..1023
    lslot[b] = s * 16;
    {
      int r = s >> 4, c = s & 15;
      int gc = (c & 8) | ((c & 7) ^ (r & 7));
      koff[b] = r * 256 + gc * 16;
    }
    {
      int r = s >> 3, c = s & 7;
      int gc = c ^ (r & 7);
      voff[b] = r * 4096 + gc * 16;
    }
  }
  const char* KbB = (const char*)Kb;
  const char* VbB = (const char*)Vb;
  char* KsB = (char*)Ks;
  char* VsB = (char*)Vs;

  const int ktmax = 2 * qt + 1;

  for (int kt = 0; kt <= ktmax; ++kt) {
    const int k0 = kt * 64;
    if (kt) __syncthreads();
#pragma unroll
    for (int b = 0; b < 4; b++) {
      gld_lds16(KbB + (size_t)k0 * 256 + koff[b], KsB + lslot[b]);
      gld_lds16(VbB + (size_t)k0 * 2 + voff[b], VsB + lslot[b]);
    }
    __syncthreads();

    f32x4 st[2][4];
#pragma unroll
    for (int i = 0; i < 2; i++)
#pragma unroll
      for (int j = 0; j < 4; j++) st[i][j] = fz;
#pragma unroll
    for (int j = 0; j < 4; j++) {
      int rowk = j * 16 + l16;
#pragma unroll
      for (int t = 0; t < 4; t++) {
        int cc = t * 4 + quad;
        int ch = (cc & 8) | ((cc & 7) ^ (rowk & 7));
        bf16x8 kfr = *(const bf16x8*)(KsB + rowk * 256 + ch * 16);
        st[0][j] = MFMA16(kfr, qf[0][t], st[0][j]);
        st[1][j] = MFMA16(kfr, qf[1][t], st[1][j]);
      }
    }

    const bool do_mask = (kt >= 2 * qt);
#pragma unroll
    for (int i = 0; i < 2; i++) {
      const int qg = q0 + wave * 32 + i * 16 + l16;
      float lacc = 0.f;
#pragma unroll
      for (int j = 0; j < 4; j++) {
        float p[4];
#pragma unroll
        for (int r = 0; r < 4; r++) {
          float v = st[i][j][r];
          if (do_mask && (k0 + j * 16 + quad * 4 + r > qg)) v = -1e30f;
          p[r] = __expf(v);
        }
        lacc += (p[0] + p[1]) + (p[2] + p[3]);
        u16x4 pk = {f2bf(p[0]), f2bf(p[1]), f2bf(p[2]), f2bf(p[3])};
        *(u16x4*)&Ps[(wave * 32 + i * 16 + l16) * 72 + j * 16 + quad * 4] = pk;
      }
      l_i[i] += lacc;
    }

#pragma unroll
    for (int t = 0; t < 2; t++) {
      bf16x8 af0 = *(const bf16x8*)((char*)Ps + (wave * 32 + l16) * 144 + (t * 32 + quad * 8) * 2);
      bf16x8 af1 = *(const bf16x8*)((char*)Ps + (wave * 32 + 16 + l16) * 144 + (t * 32 + quad * 8) * 2);
#pragma unroll
      for (int j = 0; j < 8; j++) {
        int vrow = j * 16 + l16;
        int ch = (t * 4 + quad) ^ (vrow & 7);
        bf16x8 bfr = *(const bf16x8*)(VsB + vrow * 128 + ch * 16);
        o_acc[0][j] = MFMA16(af0, bfr, o_acc[0][j]);
        o_acc[1][j] = MFMA16(af1, bfr, o_acc[1][j]);
      }
    }
  }

  const int bb = bh >> 4, h = bh & 15;
#pragma unroll
  for (int i = 0; i < 2; i++) {
    float rs = l_i[i];
    rs += __shfl_xor(rs, 16);
    rs += __shfl_xor(rs, 32);
    float inv = 1.f / rs;
#pragma unroll
    for (int r = 0; r < 4; r++) {
      float invr = __shfl(inv, (lane & 48) | (quad * 4 + r), 64);
      int srow = q0 + wave * 32 + i * 16 + quad * 4 + r;
      size_t base = ((size_t)(bb * 2048 + srow)) * 2048 + h * 128;
#pragma unroll
      for (int j = 0; j < 8; j++) attn[base + j * 16 + l16] = f2bf(o_acc[i][j][r] * invr);
    }
  }
}

// ---------------------------------------------------------------------------
extern "C" void kernel_launch(void* const* d_in, const int* in_sizes, int n_in,
                              void* d_out, int out_size, void* d_ws, size_t ws_size,
                              hipStream_t stream) {
  (void)n_in; (void)out_size; (void)ws_size;
  const float* x = (const float*)d_in[0];     // [2,2048,2048] f32
  const float* cpq = (const float*)d_in[1];
  const float* cpk = (const float*)d_in[2];
  const float* cpv = (const float*)d_in[3];
  const float* cpo = (const float*)d_in[4];
  // d_in[5] = attention_mask: causal, applied analytically -> unused
  float* out = (float*)d_out;
  const int ncp = in_sizes[1];                // 32539
  const double factor = (double)(ncp - 1) / 4194303.0;

  char* ws = (char*)d_ws;
  u16* Wqkv = (u16*)(ws);                  // 6144*2048 bf16 = 25165824 B
  u16* At   = (u16*)(ws);                  // [B,S,H*D] 16MB, reuses dead Wqkv
  u16* Wo = (u16*)(ws + 25165824);         // 2048*2048 bf16 =  8388608 B
  u16* Qp = (u16*)(ws + 33554432);         // [B,H,S,D] bf16 = 16777216 B
  u16* Kp = (u16*)(ws + 50331648);         // [B,H,S,D]
  u16* Vp = (u16*)(ws + 67108864);         // [B,H,D,S]      (ends 80 MB)
  u16* xb = (u16*)d_out;                   // [4096,2048] bf16, dead before final GEMM

  prep_kernel<<<dim3(69632), dim3(256), 0, stream>>>(x, cpq, cpk, cpv, cpo, xb, Wqkv, Wo, ncp, factor);
  gemm_qkv<<<dim3(768), dim3(512), 0, stream>>>(xb, Wqkv, Qp, Kp, Vp);
  flash_attn<<<dim3(512), dim3(256), 0, stream>>>(Qp, Kp, Vp, At);
  gemm_bt<1><<<dim3(16, 32), dim3(256), 0, stream>>>(At, Wo, nullptr, nullptr, nullptr, out);
}

// Round 2
// 356.080 us; speedup vs baseline: 1.0138x; 1.0138x over previous
//
#include <hip/hip_runtime.h>
#include <stdint.h>

typedef unsigned short u16;
typedef __bf16 bf16x8 __attribute__((ext_vector_type(8)));
typedef float f32x4 __attribute__((ext_vector_type(4)));
typedef u16 u16x4 __attribute__((ext_vector_type(4)));

#define MFMA16(a, b, c) __builtin_amdgcn_mfma_f32_16x16x32_bf16((a), (b), (c), 0, 0, 0)

__device__ __forceinline__ u16 f2bf(float f) {
  uint32_t u = __builtin_bit_cast(uint32_t, f);
  u += 0x7FFFu + ((u >> 16) & 1u);  // RNE
  return (u16)(u >> 16);
}
__device__ __forceinline__ bf16x8 cvt8(f32x4 lo, f32x4 hi) {
  union { u16 u[8]; bf16x8 v; } r;
#pragma unroll
  for (int j = 0; j < 4; j++) { r.u[j] = f2bf(lo[j]); r.u[4 + j] = f2bf(hi[j]); }
  return r.v;
}
// async global->LDS, 16B per lane. LDS dest = wave-uniform base + lane*16.
__device__ __forceinline__ void gld_lds16(const void* g, void* l) {
  __builtin_amdgcn_global_load_lds(
      (const __attribute__((address_space(1))) uint32_t*)g,
      (__attribute__((address_space(3))) uint32_t*)l, 16, 0, 0);
}

// ---------------------------------------------------------------------------
// Fused prep: blocks [0,65536) spline-interp the 4 weight curves (n=32539
// f32 cps -> 4.2M bf16 samples each); blocks [65536,69632) convert x f32->bf16.
// ---------------------------------------------------------------------------
__global__ void prep_kernel(const float* __restrict__ x, const float* __restrict__ cpq,
                            const float* __restrict__ cpk, const float* __restrict__ cpv,
                            const float* __restrict__ cpo, u16* __restrict__ xb,
                            u16* __restrict__ Wqkv, u16* __restrict__ Wo,
                            int n, double factor) {
  int blk = blockIdx.x;
  if (blk < 65536) {
    int idx = blk * 256 + threadIdx.x;           // < 4*4194304
    int w = idx >> 22;
    int i = idx & 4194303;
    const float* cp = (w == 0) ? cpq : (w == 1) ? cpk : (w == 2) ? cpv : cpo;
    double u = (double)i * factor;               // f64: f32 too coarse here
    int i0 = (int)u;
    if (i0 > n - 2) i0 = n - 2;
    float fr = (float)(u - (double)i0);
    float f0 = cp[i0], f1 = cp[i0 + 1];
    u16 bv = f2bf(f0 + fr * (f1 - f0));
    if (w < 3) Wqkv[idx] = bv; else Wo[i] = bv;
  } else {
    size_t i = ((size_t)(blk - 65536) * 256 + threadIdx.x) * 8;
    const f32x4* p = (const f32x4*)(x + i);
    *(bf16x8*)(xb + i) = cvt8(p[0], p[1]);
  }
}

// ---------------------------------------------------------------------------
// QKV projection GEMM, round-2 pipeline.
// C[M=4096, N=6144] = A[M,2048] @ B[N,2048]^T, bf16 in, f32 acc.
// BM=128 x BN=256 x BK=64, 512 threads (8 waves: wm=wave&1, wn=wave>>1,
// per-wave 64x64 output -> acc[4][4], SAME frag math as the proven R0 kernel).
// Grid 768 = 32m x 24n = 3 exact rounds of 256 CUs.
// LDS: TRIPLE-buffered As(16K)+Bs(32K) = 144 KiB -> 1 block/CU, 8 waves.
// Ledger (per-thread loads; 6/tile):
//   prologue: stage(0->buf0) stage(1->buf1) ; vmcnt(6) [tile0 done] ; barrier
//   body(t):  stage(t+2 -> buf[(t+2)%3])    [buf's last reader was tile t-1,
//             retired before previous barrier]
//             ds_read tile t (16 x b128, PROVEN BK=64 swizzle, 0 conflicts)
//             32 MFMA under setprio
//             vmcnt(6)  [tile t+1 done - issued ONE FULL BODY earlier;
//                        t+2's 6 loads stay in flight - never drained]
//             s_barrier + sched_barrier(0)
//   tail: body(30) waits vmcnt(0); body(31) no wait/barrier.
// Swizzle (both-sides involution, R0-verified): chunk gc = c ^ (r&7) on the
// global source, ds_read ch = (t*4+quad) ^ (row&7); k-step-1 offset = ^64.
// XCD-chunked block map (768%8==0 -> bijective): per XCD, n-inner so the
// 512KB A-panel stays L2-resident.
// ---------------------------------------------------------------------------
__global__ __launch_bounds__(512, 2)
void gemm_qkv(const u16* __restrict__ A, const u16* __restrict__ B,
              u16* __restrict__ oQ, u16* __restrict__ oK, u16* __restrict__ oV) {
  __shared__ __align__(16) u16 As[3 * 128 * 64];   // 3 x 16384 B
  __shared__ __align__(16) u16 Bs[3 * 256 * 64];   // 3 x 32768 B
  const int tid = threadIdx.x;
  const int wave = tid >> 6, lane = tid & 63, quad = lane >> 4, l16 = lane & 15;
  const int wm = wave & 1, wn = wave >> 1;

  const int z = blockIdx.x;
  const int wg = (z & 7) * 96 + (z >> 3);  // XCD chunking
  const int mt = wg / 24, nt = wg - mt * 24;
  const int m0 = mt * 128, n0 = nt * 256;

  // stage slots: A = 1024 16B-chunks (2/thread), B = 2048 (4/thread)
  size_t aoffg[2], boffg[4];
  int lA[2], lB[4];
#pragma unroll
  for (int u = 0; u < 2; u++) {
    int s = u * 512 + tid, r = s >> 3, c = s & 7, gc = c ^ (r & 7);
    lA[u] = s * 16;
    aoffg[u] = (size_t)(m0 + r) * 4096 + gc * 16;
  }
#pragma unroll
  for (int u = 0; u < 4; u++) {
    int s = u * 512 + tid, r = s >> 3, c = s & 7, gc = c ^ (r & 7);
    lB[u] = s * 16;
    boffg[u] = (size_t)(n0 + r) * 4096 + gc * 16;
  }

  // ds_read byte offsets for k-step 0; k-step 1 = offset ^ 64 (chunk ^ 4)
  int roA[4], roB[4];
#pragma unroll
  for (int mi = 0; mi < 4; mi++) {
    int row = wm * 64 + mi * 16 + l16;
    roA[mi] = row * 128 + ((quad ^ (row & 7)) * 16);
  }
#pragma unroll
  for (int nj = 0; nj < 4; nj++) {
    int row = wn * 64 + nj * 16 + l16;
    roB[nj] = row * 128 + ((quad ^ (row & 7)) * 16);
  }

  const char* Ab = (const char*)A;
  const char* Bb = (const char*)B;
  char* AsB = (char*)As;
  char* BsB = (char*)Bs;

  f32x4 acc[4][4];
  const f32x4 fz = {0.f, 0.f, 0.f, 0.f};
#pragma unroll
  for (int i = 0; i < 4; i++)
#pragma unroll
    for (int j = 0; j < 4; j++) acc[i][j] = fz;

#define QKV_STAGE(TT, NX)                                                     \
  do {                                                                        \
    size_t kb = (size_t)(TT) * 128;                                           \
    gld_lds16(Ab + aoffg[0] + kb, AsB + (NX) * 16384 + lA[0]);                \
    gld_lds16(Ab + aoffg[1] + kb, AsB + (NX) * 16384 + lA[1]);                \
    gld_lds16(Bb + boffg[0] + kb, BsB + (NX) * 32768 + lB[0]);                \
    gld_lds16(Bb + boffg[1] + kb, BsB + (NX) * 32768 + lB[1]);                \
    gld_lds16(Bb + boffg[2] + kb, BsB + (NX) * 32768 + lB[2]);                \
    gld_lds16(Bb + boffg[3] + kb, BsB + (NX) * 32768 + lB[3]);                \
  } while (0)

// WM: 6 = vmcnt(6)+barrier, 0 = vmcnt(0)+barrier, -1 = none (last tile)
#define QKV_BODY(T, CUR, NX, STG, WM)                                         \
  do {                                                                        \
    if (STG) QKV_STAGE((T) + 2, NX);                                          \
    _Pragma("unroll") for (int t = 0; t < 2; t++) {                           \
      bf16x8 af[4], bfv[4];                                                   \
      _Pragma("unroll") for (int mi = 0; mi < 4; mi++)                        \
          af[mi] = *(const bf16x8*)(AsB + (CUR) * 16384 + (roA[mi] ^ (t * 64))); \
      _Pragma("unroll") for (int nj = 0; nj < 4; nj++)                        \
          bfv[nj] = *(const bf16x8*)(BsB + (CUR) * 32768 + (roB[nj] ^ (t * 64))); \
      __builtin_amdgcn_s_setprio(1);                                          \
      _Pragma("unroll") for (int mi = 0; mi < 4; mi++)                        \
          _Pragma("unroll") for (int nj = 0; nj < 4; nj++)                    \
              acc[mi][nj] = MFMA16(af[mi], bfv[nj], acc[mi][nj]);             \
      __builtin_amdgcn_s_setprio(0);                                          \
    }                                                                         \
    if ((WM) == 6) asm volatile("s_waitcnt vmcnt(6)" ::: "memory");           \
    else if ((WM) == 0) asm volatile("s_waitcnt vmcnt(0)" ::: "memory");      \
    if ((WM) >= 0) {                                                          \
      __builtin_amdgcn_s_barrier();                                           \
      __builtin_amdgcn_sched_barrier(0);                                      \
    }                                                                         \
  } while (0)

  // prologue: tiles 0,1 -> buf 0,1; wait tile0 (tile1's 6 remain in flight)
  QKV_STAGE(0, 0);
  QKV_STAGE(1, 1);
  asm volatile("s_waitcnt vmcnt(6)" ::: "memory");
  __builtin_amdgcn_s_barrier();
  __builtin_amdgcn_sched_barrier(0);

  for (int t = 0; t < 30; t += 3) {   // tiles 0..29; stages tiles 2..31
    QKV_BODY(t, 0, 2, true, 6);
    QKV_BODY(t + 1, 1, 0, true, 6);
    QKV_BODY(t + 2, 2, 1, true, 6);
  }
  QKV_BODY(30, 0, 2, false, 0);       // drain tile31's loads
  QKV_BODY(31, 1, 0, false, -1);
#undef QKV_BODY
#undef QKV_STAGE

  // epilogue: C frag layout col=lane&15 (n), row=quad*4+reg (m). Verified R0.
  const float qscale = 0.08838834764831845f;  // folded into Q
#pragma unroll
  for (int j = 0; j < 4; j++) {
    int nb = n0 + wn * 64 + j * 16;
    int sel = nb >> 11;                      // 0=Q 1=K 2=V (uniform per block)
    int h = (nb >> 7) & 15;
    int d = (nb & 127) + l16;
#pragma unroll
    for (int i = 0; i < 4; i++) {
      int mrow = m0 + wm * 64 + i * 16 + quad * 4;
      int bq = mrow >> 11, srow = mrow & 2047;
      if (sel == 2) {
        u16x4 pk = {f2bf(acc[i][j][0]), f2bf(acc[i][j][1]),
                    f2bf(acc[i][j][2]), f2bf(acc[i][j][3])};
        *(u16x4*)&oV[(size_t)(((bq << 4) + h) * 128 + d) * 2048 + srow] = pk;
      } else if (sel == 0) {
        int base = ((bq << 4) + h) * 2048;
#pragma unroll
        for (int r = 0; r < 4; r++)
          oQ[(size_t)(base + srow + r) * 128 + d] = f2bf(acc[i][j][r] * qscale);
      } else {
        int base = ((bq << 4) + h) * 2048;
#pragma unroll
        for (int r = 0; r < 4; r++)
          oK[(size_t)(base + srow + r) * 128 + d] = f2bf(acc[i][j][r]);
      }
    }
  }
}

// ---------------------------------------------------------------------------
// C[M,N] = A[M,2048] @ B[N,2048]^T, bf16 in, f32 acc. 128x128 tile, BK=64.
// Proven 2-barrier kernel, used for the output projection (MODE 1).
// ---------------------------------------------------------------------------
template <int MODE>
__global__ __launch_bounds__(256, 2)
void gemm_bt(const u16* __restrict__ A, const u16* __restrict__ B,
             u16* __restrict__ oQ, u16* __restrict__ oK, u16* __restrict__ oV,
             float* __restrict__ oC) {
  constexpr int KD = 2048;
  __shared__ __align__(16) u16 As[128 * 64];
  __shared__ __align__(16) u16 Bs[128 * 64];
  const int tid = threadIdx.x;
  const int wave = tid >> 6, lane = tid & 63, quad = lane >> 4, l16 = lane & 15;
  const int wm = wave & 1, wn = wave >> 1;
  const int m0 = blockIdx.y * 128, n0 = blockIdx.x * 128;

  size_t aoff[4], boff[4];
  int lslot[4];
#pragma unroll
  for (int b = 0; b < 4; b++) {
    int s = wave * 256 + b * 64 + lane;  // chunk slot 0..1023 (16B chunks)
    int r = s >> 3, c = s & 7, gc = c ^ (r & 7);
    lslot[b] = s * 16;
    aoff[b] = (size_t)(m0 + r) * (KD * 2) + gc * 16;
    boff[b] = (size_t)(n0 + r) * (KD * 2) + gc * 16;
  }
  const char* Ab = (const char*)A;
  const char* Bb = (const char*)B;
  char* AsB = (char*)As;
  char* BsB = (char*)Bs;

  f32x4 acc[4][4];
  const f32x4 fz = {0.f, 0.f, 0.f, 0.f};
#pragma unroll
  for (int i = 0; i < 4; i++)
#pragma unroll
    for (int j = 0; j < 4; j++) acc[i][j] = fz;

  for (int kt = 0; kt < KD / 64; ++kt) {
    if (kt) __syncthreads();
#pragma unroll
    for (int b = 0; b < 4; b++) {
      gld_lds16(Ab + aoff[b], AsB + lslot[b]);
      gld_lds16(Bb + boff[b], BsB + lslot[b]);
      aoff[b] += 128;
      boff[b] += 128;
    }
    __syncthreads();
#pragma unroll
    for (int t = 0; t < 2; t++) {
      bf16x8 af[4], bfb[4];
#pragma unroll
      for (int i = 0; i < 4; i++) {
        int row = wm * 64 + i * 16 + l16;
        int ch = (t * 4 + quad) ^ (row & 7);
        af[i] = *(const bf16x8*)(AsB + row * 128 + ch * 16);
      }
#pragma unroll
      for (int j = 0; j < 4; j++) {
        int row = wn * 64 + j * 16 + l16;
        int ch = (t * 4 + quad) ^ (row & 7);
        bfb[j] = *(const bf16x8*)(BsB + row * 128 + ch * 16);
      }
#pragma unroll
      for (int i = 0; i < 4; i++)
#pragma unroll
        for (int j = 0; j < 4; j++) acc[i][j] = MFMA16(af[i], bfb[j], acc[i][j]);
    }
  }

  if (MODE == 0) {
    const float qscale = 0.08838834764831845f;
#pragma unroll
    for (int j = 0; j < 4; j++) {
      int nb = n0 + wn * 64 + j * 16;
      int sel = nb >> 11;
      int h = (nb >> 7) & 15;
      int d = (nb & 127) + l16;
#pragma unroll
      for (int i = 0; i < 4; i++) {
        int mrow = m0 + wm * 64 + i * 16 + quad * 4;
        int bq = mrow >> 11, srow = mrow & 2047;
        if (sel == 2) {
          u16x4 pk = {f2bf(acc[i][j][0]), f2bf(acc[i][j][1]),
                      f2bf(acc[i][j][2]), f2bf(acc[i][j][3])};
          *(u16x4*)&oV[(size_t)(((bq << 4) + h) * 128 + d) * 2048 + srow] = pk;
        } else if (sel == 0) {
          int base = ((bq << 4) + h) * 2048;
#pragma unroll
          for (int r = 0; r < 4; r++)
            oQ[(size_t)(base + srow + r) * 128 + d] = f2bf(acc[i][j][r] * qscale);
        } else {
          int base = ((bq << 4) + h) * 2048;
#pragma unroll
          for (int r = 0; r < 4; r++)
            oK[(size_t)(base + srow + r) * 128 + d] = f2bf(acc[i][j][r]);
        }
      }
    }
  } else {
#pragma unroll
    for (int j = 0; j < 4; j++) {
      int col = n0 + wn * 64 + j * 16 + l16;
#pragma unroll
      for (int i = 0; i < 4; i++) {
        int mrow = m0 + wm * 64 + i * 16 + quad * 4;
#pragma unroll
        for (int r = 0; r < 4; r++) oC[(size_t)(mrow + r) * 2048 + col] = acc[i][j][r];
      }
    }
  }
}

// ---------------------------------------------------------------------------
// Causal flash attention, Bc=64, max-free softmax, TRANSPOSED QK (unchanged).
// ---------------------------------------------------------------------------
__global__ __launch_bounds__(256, 2)
void flash_attn(const u16* __restrict__ Q, const u16* __restrict__ Kg,
                const u16* __restrict__ Vt, u16* __restrict__ attn) {
  __shared__ __align__(16) u16 Ks[64 * 128];
  __shared__ __align__(16) u16 Vs[128 * 64];
  __shared__ __align__(16) u16 Ps[128 * 72];
  const int tid = threadIdx.x;
  const int wave = tid >> 6, lane = tid & 63, quad = lane >> 4, l16 = lane & 15;
  const int L = blockIdx.x;
  const int bh = L & 31;
  const int qi = (L >> 5) & 7;
  const int qt = (L >= 256) ? (15 - qi) : qi;
  const int q0 = qt * 128;
  const u16* Qb = Q + (size_t)bh * 2048 * 128;
  const u16* Kb = Kg + (size_t)bh * 2048 * 128;
  const u16* Vb = Vt + (size_t)bh * 128 * 2048;

  bf16x8 qf[2][4];
#pragma unroll
  for (int i = 0; i < 2; i++) {
    int row = q0 + wave * 32 + i * 16 + l16;
#pragma unroll
    for (int t = 0; t < 4; t++)
      qf[i][t] = *(const bf16x8*)(Qb + (size_t)row * 128 + t * 32 + quad * 8);
  }

  f32x4 o_acc[2][8];
  const f32x4 fz = {0.f, 0.f, 0.f, 0.f};
#pragma unroll
  for (int i = 0; i < 2; i++)
#pragma unroll
    for (int j = 0; j < 8; j++) o_acc[i][j] = fz;
  float l_i[2] = {0.f, 0.f};

  int koff[4], voff[4], lslot[4];
#pragma unroll
  for (int b = 0; b < 4; b++) {
    int s = wave * 256 + b * 64 + lane;  // 0..1023
    lslot[b] = s * 16;
    {
      int r = s >> 4, c = s & 15;
      int gc = (c & 8) | ((c & 7) ^ (r & 7));
      koff[b] = r * 256 + gc * 16;
    }
    {
      int r = s >> 3, c = s & 7;
      int gc = c ^ (r & 7);
      voff[b] = r * 4096 + gc * 16;
    }
  }
  const char* KbB = (const char*)Kb;
  const char* VbB = (const char*)Vb;
  char* KsB = (char*)Ks;
  char* VsB = (char*)Vs;

  const int ktmax = 2 * qt + 1;

  for (int kt = 0; kt <= ktmax; ++kt) {
    const int k0 = kt * 64;
    if (kt) __syncthreads();
#pragma unroll
    for (int b = 0; b < 4; b++) {
      gld_lds16(KbB + (size_t)k0 * 256 + koff[b], KsB + lslot[b]);
      gld_lds16(VbB + (size_t)k0 * 2 + voff[b], VsB + lslot[b]);
    }
    __syncthreads();

    f32x4 st[2][4];
#pragma unroll
    for (int i = 0; i < 2; i++)
#pragma unroll
      for (int j = 0; j < 4; j++) st[i][j] = fz;
#pragma unroll
    for (int j = 0; j < 4; j++) {
      int rowk = j * 16 + l16;
#pragma unroll
      for (int t = 0; t < 4; t++) {
        int cc = t * 4 + quad;
        int ch = (cc & 8) | ((cc & 7) ^ (rowk & 7));
        bf16x8 kfr = *(const bf16x8*)(KsB + rowk * 256 + ch * 16);
        st[0][j] = MFMA16(kfr, qf[0][t], st[0][j]);
        st[1][j] = MFMA16(kfr, qf[1][t], st[1][j]);
      }
    }

    const bool do_mask = (kt >= 2 * qt);
#pragma unroll
    for (int i = 0; i < 2; i++) {
      const int qg = q0 + wave * 32 + i * 16 + l16;
      float lacc = 0.f;
#pragma unroll
      for (int j = 0; j < 4; j++) {
        float p[4];
#pragma unroll
        for (int r = 0; r < 4; r++) {
          float v = st[i][j][r];
          if (do_mask && (k0 + j * 16 + quad * 4 + r > qg)) v = -1e30f;
          p[r] = __expf(v);
        }
        lacc += (p[0] + p[1]) + (p[2] + p[3]);
        u16x4 pk = {f2bf(p[0]), f2bf(p[1]), f2bf(p[2]), f2bf(p[3])};
        *(u16x4*)&Ps[(wave * 32 + i * 16 + l16) * 72 + j * 16 + quad * 4] = pk;
      }
      l_i[i] += lacc;
    }

#pragma unroll
    for (int t = 0; t < 2; t++) {
      bf16x8 af0 = *(const bf16x8*)((char*)Ps + (wave * 32 + l16) * 144 + (t * 32 + quad * 8) * 2);
      bf16x8 af1 = *(const bf16x8*)((char*)Ps + (wave * 32 + 16 + l16) * 144 + (t * 32 + quad * 8) * 2);
#pragma unroll
      for (int j = 0; j < 8; j++) {
        int vrow = j * 16 + l16;
        int ch = (t * 4 + quad) ^ (vrow & 7);
        bf16x8 bfr = *(const bf16x8*)(VsB + vrow * 128 + ch * 16);
        o_acc[0][j] = MFMA16(af0, bfr, o_acc[0][j]);
        o_acc[1][j] = MFMA16(af1, bfr, o_acc[1][j]);
      }
    }
  }

  const int bb = bh >> 4, h = bh & 15;
#pragma unroll
  for (int i = 0; i < 2; i++) {
    float rs = l_i[i];
    rs += __shfl_xor(rs, 16);
    rs += __shfl_xor(rs, 32);
    float inv = 1.f / rs;
#pragma unroll
    for (int r = 0; r < 4; r++) {
      float invr = __shfl(inv, (lane & 48) | (quad * 4 + r), 64);
      int srow = q0 + wave * 32 + i * 16 + quad * 4 + r;
      size_t base = ((size_t)(bb * 2048 + srow)) * 2048 + h * 128;
#pragma unroll
      for (int j = 0; j < 8; j++) attn[base + j * 16 + l16] = f2bf(o_acc[i][j][r] * invr);
    }
  }
}

// ---------------------------------------------------------------------------
extern "C" void kernel_launch(void* const* d_in, const int* in_sizes, int n_in,
                              void* d_out, int out_size, void* d_ws, size_t ws_size,
                              hipStream_t stream) {
  (void)n_in; (void)out_size; (void)ws_size;
  const float* x = (const float*)d_in[0];     // [2,2048,2048] f32
  const float* cpq = (const float*)d_in[1];
  const float* cpk = (const float*)d_in[2];
  const float* cpv = (const float*)d_in[3];
  const float* cpo = (const float*)d_in[4];
  // d_in[5] = attention_mask: causal, applied analytically -> unused
  float* out = (float*)d_out;
  const int ncp = in_sizes[1];                // 32539
  const double factor = (double)(ncp - 1) / 4194303.0;

  char* ws = (char*)d_ws;
  u16* Wqkv = (u16*)(ws);                  // 6144*2048 bf16 = 25165824 B
  u16* At   = (u16*)(ws);                  // [B,S,H*D] 16MB, reuses dead Wqkv
  u16* Wo = (u16*)(ws + 25165824);         // 2048*2048 bf16 =  8388608 B
  u16* Qp = (u16*)(ws + 33554432);         // [B,H,S,D] bf16 = 16777216 B
  u16* Kp = (u16*)(ws + 50331648);         // [B,H,S,D]
  u16* Vp = (u16*)(ws + 67108864);         // [B,H,D,S]      (ends 80 MB)
  u16* xb = (u16*)d_out;                   // [4096,2048] bf16, dead before final GEMM

  prep_kernel<<<dim3(69632), dim3(256), 0, stream>>>(x, cpq, cpk, cpv, cpo, xb, Wqkv, Wo, ncp, factor);
  gemm_qkv<<<dim3(768), dim3(512), 0, stream>>>(xb, Wqkv, Qp, Kp, Vp);
  flash_attn<<<dim3(512), dim3(256), 0, stream>>>(Qp, Kp, Vp, At);
  gemm_bt<1><<<dim3(16, 32), dim3(256), 0, stream>>>(At, Wo, nullptr, nullptr, nullptr, out);
}

// Round 3
// 355.603 us; speedup vs baseline: 1.0152x; 1.0013x over previous
//
#include <hip/hip_runtime.h>
#include <stdint.h>

typedef unsigned short u16;
typedef __bf16 bf16x8 __attribute__((ext_vector_type(8)));
typedef float f32x4 __attribute__((ext_vector_type(4)));
typedef u16 u16x4 __attribute__((ext_vector_type(4)));

#define MFMA16(a, b, c) __builtin_amdgcn_mfma_f32_16x16x32_bf16((a), (b), (c), 0, 0, 0)

__device__ __forceinline__ u16 f2bf(float f) {
  uint32_t u = __builtin_bit_cast(uint32_t, f);
  u += 0x7FFFu + ((u >> 16) & 1u);  // RNE
  return (u16)(u >> 16);
}
__device__ __forceinline__ bf16x8 cvt8(f32x4 lo, f32x4 hi) {
  union { u16 u[8]; bf16x8 v; } r;
#pragma unroll
  for (int j = 0; j < 4; j++) { r.u[j] = f2bf(lo[j]); r.u[4 + j] = f2bf(hi[j]); }
  return r.v;
}
// async global->LDS, 16B per lane. LDS dest = wave-uniform base + lane*16.
__device__ __forceinline__ void gld_lds16(const void* g, void* l) {
  __builtin_amdgcn_global_load_lds(
      (const __attribute__((address_space(1))) uint32_t*)g,
      (__attribute__((address_space(3))) uint32_t*)l, 16, 0, 0);
}

// ---------------------------------------------------------------------------
// Fused prep: blocks [0,65536) spline-interp the 4 weight curves (n=32539
// f32 cps -> 4.2M bf16 samples each); blocks [65536,69632) convert x f32->bf16.
// ---------------------------------------------------------------------------
__global__ void prep_kernel(const float* __restrict__ x, const float* __restrict__ cpq,
                            const float* __restrict__ cpk, const float* __restrict__ cpv,
                            const float* __restrict__ cpo, u16* __restrict__ xb,
                            u16* __restrict__ Wqkv, u16* __restrict__ Wo,
                            int n, double factor) {
  int blk = blockIdx.x;
  if (blk < 65536) {
    int idx = blk * 256 + threadIdx.x;           // < 4*4194304
    int w = idx >> 22;
    int i = idx & 4194303;
    const float* cp = (w == 0) ? cpq : (w == 1) ? cpk : (w == 2) ? cpv : cpo;
    double u = (double)i * factor;               // f64: f32 too coarse here
    int i0 = (int)u;
    if (i0 > n - 2) i0 = n - 2;
    float fr = (float)(u - (double)i0);
    float f0 = cp[i0], f1 = cp[i0 + 1];
    u16 bv = f2bf(f0 + fr * (f1 - f0));
    if (w < 3) Wqkv[idx] = bv; else Wo[i] = bv;
  } else {
    size_t i = ((size_t)(blk - 65536) * 256 + threadIdx.x) * 8;
    const f32x4* p = (const f32x4*)(x + i);
    *(bf16x8*)(xb + i) = cvt8(p[0], p[1]);
  }
}

// ---------------------------------------------------------------------------
// QKV projection GEMM, round-3: R2 pipelined body + R0-style L2-resident map.
// C[M=4096, N=6144] = A[M,2048] @ B[N,2048]^T, bf16 in, f32 acc.
// BM=128 x BN=256 x BK=64, 512 threads (8 waves: wm=wave&1, wn=wave>>1,
// per-wave 64x64 output -> acc[4][4]).
// Grid dim3(24, 32): nt = blockIdx.x (BN=256), mt = blockIdx.y (BM=128).
// KEY: inner width 24 with round-robin XCD assignment (XCD = linear_id % 8;
// 24*y % 8 == 0) gives each XCD nt in {x, x+8, x+16} -> its 3 B-panels
// (3 MB) stay L2-RESIDENT for the whole kernel, A K-slices are shared by the
// 3 co-resident nt-blocks. This is the property that gave R0 its 103 MB
// FETCH; the R2 chunk map broke it (307 MB -> BW-bound).
// LDS: TRIPLE-buffered As(16K)+Bs(32K) = 144 KiB -> 1 block/CU, 8 waves.
// Ledger (per-thread loads; 6/tile):
//   prologue: stage(0->buf0) stage(1->buf1) ; vmcnt(6) [tile0 done] ; barrier
//   body(t):  stage(t+2 -> buf[(t+2)%3]) ; ds_read tile t (16 x b128, proven
//             swizzle) ; 32 MFMA (setprio) ; vmcnt(6) [tile t+1 done, t+2 in
//             flight -- never drained] ; s_barrier + sched_barrier(0)
//   tail: body(30) waits vmcnt(0); body(31) no wait/barrier.
// ---------------------------------------------------------------------------
__global__ __launch_bounds__(512, 2)
void gemm_qkv(const u16* __restrict__ A, const u16* __restrict__ B,
              u16* __restrict__ oQ, u16* __restrict__ oK, u16* __restrict__ oV) {
  __shared__ __align__(16) u16 As[3 * 128 * 64];   // 3 x 16384 B
  __shared__ __align__(16) u16 Bs[3 * 256 * 64];   // 3 x 32768 B
  const int tid = threadIdx.x;
  const int wave = tid >> 6, lane = tid & 63, quad = lane >> 4, l16 = lane & 15;
  const int wm = wave & 1, wn = wave >> 1;

  const int m0 = blockIdx.y * 128, n0 = blockIdx.x * 256;

  // stage slots: A = 1024 16B-chunks (2/thread), B = 2048 (4/thread)
  size_t aoffg[2], boffg[4];
  int lA[2], lB[4];
#pragma unroll
  for (int u = 0; u < 2; u++) {
    int s = u * 512 + tid, r = s >> 3, c = s & 7, gc = c ^ (r & 7);
    lA[u] = s * 16;
    aoffg[u] = (size_t)(m0 + r) * 4096 + gc * 16;
  }
#pragma unroll
  for (int u = 0; u < 4; u++) {
    int s = u * 512 + tid, r = s >> 3, c = s & 7, gc = c ^ (r & 7);
    lB[u] = s * 16;
    boffg[u] = (size_t)(n0 + r) * 4096 + gc * 16;
  }

  // ds_read byte offsets for k-step 0; k-step 1 = offset ^ 64 (chunk ^ 4)
  int roA[4], roB[4];
#pragma unroll
  for (int mi = 0; mi < 4; mi++) {
    int row = wm * 64 + mi * 16 + l16;
    roA[mi] = row * 128 + ((quad ^ (row & 7)) * 16);
  }
#pragma unroll
  for (int nj = 0; nj < 4; nj++) {
    int row = wn * 64 + nj * 16 + l16;
    roB[nj] = row * 128 + ((quad ^ (row & 7)) * 16);
  }

  const char* Ab = (const char*)A;
  const char* Bb = (const char*)B;
  char* AsB = (char*)As;
  char* BsB = (char*)Bs;

  f32x4 acc[4][4];
  const f32x4 fz = {0.f, 0.f, 0.f, 0.f};
#pragma unroll
  for (int i = 0; i < 4; i++)
#pragma unroll
    for (int j = 0; j < 4; j++) acc[i][j] = fz;

#define QKV_STAGE(TT, NX)                                                     \
  do {                                                                        \
    size_t kb = (size_t)(TT) * 128;                                           \
    gld_lds16(Ab + aoffg[0] + kb, AsB + (NX) * 16384 + lA[0]);                \
    gld_lds16(Ab + aoffg[1] + kb, AsB + (NX) * 16384 + lA[1]);                \
    gld_lds16(Bb + boffg[0] + kb, BsB + (NX) * 32768 + lB[0]);                \
    gld_lds16(Bb + boffg[1] + kb, BsB + (NX) * 32768 + lB[1]);                \
    gld_lds16(Bb + boffg[2] + kb, BsB + (NX) * 32768 + lB[2]);                \
    gld_lds16(Bb + boffg[3] + kb, BsB + (NX) * 32768 + lB[3]);                \
  } while (0)

// WM: 6 = vmcnt(6)+barrier, 0 = vmcnt(0)+barrier, -1 = none (last tile)
#define QKV_BODY(T, CUR, NX, STG, WM)                                         \
  do {                                                                        \
    if (STG) QKV_STAGE((T) + 2, NX);                                          \
    _Pragma("unroll") for (int t = 0; t < 2; t++) {                           \
      bf16x8 af[4], bfv[4];                                                   \
      _Pragma("unroll") for (int mi = 0; mi < 4; mi++)                        \
          af[mi] = *(const bf16x8*)(AsB + (CUR) * 16384 + (roA[mi] ^ (t * 64))); \
      _Pragma("unroll") for (int nj = 0; nj < 4; nj++)                        \
          bfv[nj] = *(const bf16x8*)(BsB + (CUR) * 32768 + (roB[nj] ^ (t * 64))); \
      __builtin_amdgcn_s_setprio(1);                                          \
      _Pragma("unroll") for (int mi = 0; mi < 4; mi++)                        \
          _Pragma("unroll") for (int nj = 0; nj < 4; nj++)                    \
              acc[mi][nj] = MFMA16(af[mi], bfv[nj], acc[mi][nj]);             \
      __builtin_amdgcn_s_setprio(0);                                          \
    }                                                                         \
    if ((WM) == 6) asm volatile("s_waitcnt vmcnt(6)" ::: "memory");           \
    else if ((WM) == 0) asm volatile("s_waitcnt vmcnt(0)" ::: "memory");      \
    if ((WM) >= 0) {                                                          \
      __builtin_amdgcn_s_barrier();                                           \
      __builtin_amdgcn_sched_barrier(0);                                      \
    }                                                                         \
  } while (0)

  // prologue: tiles 0,1 -> buf 0,1; wait tile0 (tile1's 6 remain in flight)
  QKV_STAGE(0, 0);
  QKV_STAGE(1, 1);
  asm volatile("s_waitcnt vmcnt(6)" ::: "memory");
  __builtin_amdgcn_s_barrier();
  __builtin_amdgcn_sched_barrier(0);

  for (int t = 0; t < 30; t += 3) {   // tiles 0..29; stages tiles 2..31
    QKV_BODY(t, 0, 2, true, 6);
    QKV_BODY(t + 1, 1, 0, true, 6);
    QKV_BODY(t + 2, 2, 1, true, 6);
  }
  QKV_BODY(30, 0, 2, false, 0);       // drain tile31's loads
  QKV_BODY(31, 1, 0, false, -1);
#undef QKV_BODY
#undef QKV_STAGE

  // epilogue: C frag layout col=lane&15 (n), row=quad*4+reg (m). Verified R0.
  const float qscale = 0.08838834764831845f;  // folded into Q
#pragma unroll
  for (int j = 0; j < 4; j++) {
    int nb = n0 + wn * 64 + j * 16;
    int sel = nb >> 11;                      // 0=Q 1=K 2=V
    int h = (nb >> 7) & 15;
    int d = (nb & 127) + l16;
#pragma unroll
    for (int i = 0; i < 4; i++) {
      int mrow = m0 + wm * 64 + i * 16 + quad * 4;
      int bq = mrow >> 11, srow = mrow & 2047;
      if (sel == 2) {
        u16x4 pk = {f2bf(acc[i][j][0]), f2bf(acc[i][j][1]),
                    f2bf(acc[i][j][2]), f2bf(acc[i][j][3])};
        *(u16x4*)&oV[(size_t)(((bq << 4) + h) * 128 + d) * 2048 + srow] = pk;
      } else if (sel == 0) {
        int base = ((bq << 4) + h) * 2048;
#pragma unroll
        for (int r = 0; r < 4; r++)
          oQ[(size_t)(base + srow + r) * 128 + d] = f2bf(acc[i][j][r] * qscale);
      } else {
        int base = ((bq << 4) + h) * 2048;
#pragma unroll
        for (int r = 0; r < 4; r++)
          oK[(size_t)(base + srow + r) * 128 + d] = f2bf(acc[i][j][r]);
      }
    }
  }
}

// ---------------------------------------------------------------------------
// C[M,N] = A[M,2048] @ B[N,2048]^T, bf16 in, f32 acc. 128x128 tile, BK=64.
// Proven 2-barrier kernel, used for the output projection (MODE 1).
// ---------------------------------------------------------------------------
template <int MODE>
__global__ __launch_bounds__(256, 2)
void gemm_bt(const u16* __restrict__ A, const u16* __restrict__ B,
             u16* __restrict__ oQ, u16* __restrict__ oK, u16* __restrict__ oV,
             float* __restrict__ oC) {
  constexpr int KD = 2048;
  __shared__ __align__(16) u16 As[128 * 64];
  __shared__ __align__(16) u16 Bs[128 * 64];
  const int tid = threadIdx.x;
  const int wave = tid >> 6, lane = tid & 63, quad = lane >> 4, l16 = lane & 15;
  const int wm = wave & 1, wn = wave >> 1;
  const int m0 = blockIdx.y * 128, n0 = blockIdx.x * 128;

  size_t aoff[4], boff[4];
  int lslot[4];
#pragma unroll
  for (int b = 0; b < 4; b++) {
    int s = wave * 256 + b * 64 + lane;  // chunk slot 0..1023 (16B chunks)
    int r = s >> 3, c = s & 7, gc = c ^ (r & 7);
    lslot[b] = s * 16;
    aoff[b] = (size_t)(m0 + r) * (KD * 2) + gc * 16;
    boff[b] = (size_t)(n0 + r) * (KD * 2) + gc * 16;
  }
  const char* Ab = (const char*)A;
  const char* Bb = (const char*)B;
  char* AsB = (char*)As;
  char* BsB = (char*)Bs;

  f32x4 acc[4][4];
  const f32x4 fz = {0.f, 0.f, 0.f, 0.f};
#pragma unroll
  for (int i = 0; i < 4; i++)
#pragma unroll
    for (int j = 0; j < 4; j++) acc[i][j] = fz;

  for (int kt = 0; kt < KD / 64; ++kt) {
    if (kt) __syncthreads();
#pragma unroll
    for (int b = 0; b < 4; b++) {
      gld_lds16(Ab + aoff[b], AsB + lslot[b]);
      gld_lds16(Bb + boff[b], BsB + lslot[b]);
      aoff[b] += 128;
      boff[b] += 128;
    }
    __syncthreads();
#pragma unroll
    for (int t = 0; t < 2; t++) {
      bf16x8 af[4], bfb[4];
#pragma unroll
      for (int i = 0; i < 4; i++) {
        int row = wm * 64 + i * 16 + l16;
        int ch = (t * 4 + quad) ^ (row & 7);
        af[i] = *(const bf16x8*)(AsB + row * 128 + ch * 16);
      }
#pragma unroll
      for (int j = 0; j < 4; j++) {
        int row = wn * 64 + j * 16 + l16;
        int ch = (t * 4 + quad) ^ (row & 7);
        bfb[j] = *(const bf16x8*)(BsB + row * 128 + ch * 16);
      }
#pragma unroll
      for (int i = 0; i < 4; i++)
#pragma unroll
        for (int j = 0; j < 4; j++) acc[i][j] = MFMA16(af[i], bfb[j], acc[i][j]);
    }
  }

  if (MODE == 0) {
    const float qscale = 0.08838834764831845f;
#pragma unroll
    for (int j = 0; j < 4; j++) {
      int nb = n0 + wn * 64 + j * 16;
      int sel = nb >> 11;
      int h = (nb >> 7) & 15;
      int d = (nb & 127) + l16;
#pragma unroll
      for (int i = 0; i < 4; i++) {
        int mrow = m0 + wm * 64 + i * 16 + quad * 4;
        int bq = mrow >> 11, srow = mrow & 2047;
        if (sel == 2) {
          u16x4 pk = {f2bf(acc[i][j][0]), f2bf(acc[i][j][1]),
                      f2bf(acc[i][j][2]), f2bf(acc[i][j][3])};
          *(u16x4*)&oV[(size_t)(((bq << 4) + h) * 128 + d) * 2048 + srow] = pk;
        } else if (sel == 0) {
          int base = ((bq << 4) + h) * 2048;
#pragma unroll
          for (int r = 0; r < 4; r++)
            oQ[(size_t)(base + srow + r) * 128 + d] = f2bf(acc[i][j][r] * qscale);
        } else {
          int base = ((bq << 4) + h) * 2048;
#pragma unroll
          for (int r = 0; r < 4; r++)
            oK[(size_t)(base + srow + r) * 128 + d] = f2bf(acc[i][j][r]);
        }
      }
    }
  } else {
#pragma unroll
    for (int j = 0; j < 4; j++) {
      int col = n0 + wn * 64 + j * 16 + l16;
#pragma unroll
      for (int i = 0; i < 4; i++) {
        int mrow = m0 + wm * 64 + i * 16 + quad * 4;
#pragma unroll
        for (int r = 0; r < 4; r++) oC[(size_t)(mrow + r) * 2048 + col] = acc[i][j][r];
      }
    }
  }
}

// ---------------------------------------------------------------------------
// Causal flash attention, Bc=64, max-free softmax, TRANSPOSED QK (unchanged).
// ---------------------------------------------------------------------------
__global__ __launch_bounds__(256, 2)
void flash_attn(const u16* __restrict__ Q, const u16* __restrict__ Kg,
                const u16* __restrict__ Vt, u16* __restrict__ attn) {
  __shared__ __align__(16) u16 Ks[64 * 128];
  __shared__ __align__(16) u16 Vs[128 * 64];
  __shared__ __align__(16) u16 Ps[128 * 72];
  const int tid = threadIdx.x;
  const int wave = tid >> 6, lane = tid & 63, quad = lane >> 4, l16 = lane & 15;
  const int L = blockIdx.x;
  const int bh = L & 31;
  const int qi = (L >> 5) & 7;
  const int qt = (L >= 256) ? (15 - qi) : qi;
  const int q0 = qt * 128;
  const u16* Qb = Q + (size_t)bh * 2048 * 128;
  const u16* Kb = Kg + (size_t)bh * 2048 * 128;
  const u16* Vb = Vt + (size_t)bh * 128 * 2048;

  bf16x8 qf[2][4];
#pragma unroll
  for (int i = 0; i < 2; i++) {
    int row = q0 + wave * 32 + i * 16 + l16;
#pragma unroll
    for (int t = 0; t < 4; t++)
      qf[i][t] = *(const bf16x8*)(Qb + (size_t)row * 128 + t * 32 + quad * 8);
  }

  f32x4 o_acc[2][8];
  const f32x4 fz = {0.f, 0.f, 0.f, 0.f};
#pragma unroll
  for (int i = 0; i < 2; i++)
#pragma unroll
    for (int j = 0; j < 8; j++) o_acc[i][j] = fz;
  float l_i[2] = {0.f, 0.f};

  int koff[4], voff[4], lslot[4];
#pragma unroll
  for (int b = 0; b < 4; b++) {
    int s = wave * 256 + b * 64 + lane;  // 0..1023
    lslot[b] = s * 16;
    {
      int r = s >> 4, c = s & 15;
      int gc = (c & 8) | ((c & 7) ^ (r & 7));
      koff[b] = r * 256 + gc * 16;
    }
    {
      int r = s >> 3, c = s & 7;
      int gc = c ^ (r & 7);
      voff[b] = r * 4096 + gc * 16;
    }
  }
  const char* KbB = (const char*)Kb;
  const char* VbB = (const char*)Vb;
  char* KsB = (char*)Ks;
  char* VsB = (char*)Vs;

  const int ktmax = 2 * qt + 1;

  for (int kt = 0; kt <= ktmax; ++kt) {
    const int k0 = kt * 64;
    if (kt) __syncthreads();
#pragma unroll
    for (int b = 0; b < 4; b++) {
      gld_lds16(KbB + (size_t)k0 * 256 + koff[b], KsB + lslot[b]);
      gld_lds16(VbB + (size_t)k0 * 2 + voff[b], VsB + lslot[b]);
    }
    __syncthreads();

    f32x4 st[2][4];
#pragma unroll
    for (int i = 0; i < 2; i++)
#pragma unroll
      for (int j = 0; j < 4; j++) st[i][j] = fz;
#pragma unroll
    for (int j = 0; j < 4; j++) {
      int rowk = j * 16 + l16;
#pragma unroll
      for (int t = 0; t < 4; t++) {
        int cc = t * 4 + quad;
        int ch = (cc & 8) | ((cc & 7) ^ (rowk & 7));
        bf16x8 kfr = *(const bf16x8*)(KsB + rowk * 256 + ch * 16);
        st[0][j] = MFMA16(kfr, qf[0][t], st[0][j]);
        st[1][j] = MFMA16(kfr, qf[1][t], st[1][j]);
      }
    }

    const bool do_mask = (kt >= 2 * qt);
#pragma unroll
    for (int i = 0; i < 2; i++) {
      const int qg = q0 + wave * 32 + i * 16 + l16;
      float lacc = 0.f;
#pragma unroll
      for (int j = 0; j < 4; j++) {
        float p[4];
#pragma unroll
        for (int r = 0; r < 4; r++) {
          float v = st[i][j][r];
          if (do_mask && (k0 + j * 16 + quad * 4 + r > qg)) v = -1e30f;
          p[r] = __expf(v);
        }
        lacc += (p[0] + p[1]) + (p[2] + p[3]);
        u16x4 pk = {f2bf(p[0]), f2bf(p[1]), f2bf(p[2]), f2bf(p[3])};
        *(u16x4*)&Ps[(wave * 32 + i * 16 + l16) * 72 + j * 16 + quad * 4] = pk;
      }
      l_i[i] += lacc;
    }

#pragma unroll
    for (int t = 0; t < 2; t++) {
      bf16x8 af0 = *(const bf16x8*)((char*)Ps + (wave * 32 + l16) * 144 + (t * 32 + quad * 8) * 2);
      bf16x8 af1 = *(const bf16x8*)((char*)Ps + (wave * 32 + 16 + l16) * 144 + (t * 32 + quad * 8) * 2);
#pragma unroll
      for (int j = 0; j < 8; j++) {
        int vrow = j * 16 + l16;
        int ch = (t * 4 + quad) ^ (vrow & 7);
        bf16x8 bfr = *(const bf16x8*)(VsB + vrow * 128 + ch * 16);
        o_acc[0][j] = MFMA16(af0, bfr, o_acc[0][j]);
        o_acc[1][j] = MFMA16(af1, bfr, o_acc[1][j]);
      }
    }
  }

  const int bb = bh >> 4, h = bh & 15;
#pragma unroll
  for (int i = 0; i < 2; i++) {
    float rs = l_i[i];
    rs += __shfl_xor(rs, 16);
    rs += __shfl_xor(rs, 32);
    float inv = 1.f / rs;
#pragma unroll
    for (int r = 0; r < 4; r++) {
      float invr = __shfl(inv, (lane & 48) | (quad * 4 + r), 64);
      int srow = q0 + wave * 32 + i * 16 + quad * 4 + r;
      size_t base = ((size_t)(bb * 2048 + srow)) * 2048 + h * 128;
#pragma unroll
      for (int j = 0; j < 8; j++) attn[base + j * 16 + l16] = f2bf(o_acc[i][j][r] * invr);
    }
  }
}

// ---------------------------------------------------------------------------
extern "C" void kernel_launch(void* const* d_in, const int* in_sizes, int n_in,
                              void* d_out, int out_size, void* d_ws, size_t ws_size,
                              hipStream_t stream) {
  (void)n_in; (void)out_size; (void)ws_size;
  const float* x = (const float*)d_in[0];     // [2,2048,2048] f32
  const float* cpq = (const float*)d_in[1];
  const float* cpk = (const float*)d_in[2];
  const float* cpv = (const float*)d_in[3];
  const float* cpo = (const float*)d_in[4];
  // d_in[5] = attention_mask: causal, applied analytically -> unused
  float* out = (float*)d_out;
  const int ncp = in_sizes[1];                // 32539
  const double factor = (double)(ncp - 1) / 4194303.0;

  char* ws = (char*)d_ws;
  u16* Wqkv = (u16*)(ws);                  // 6144*2048 bf16 = 25165824 B
  u16* At   = (u16*)(ws);                  // [B,S,H*D] 16MB, reuses dead Wqkv
  u16* Wo = (u16*)(ws + 25165824);         // 2048*2048 bf16 =  8388608 B
  u16* Qp = (u16*)(ws + 33554432);         // [B,H,S,D] bf16 = 16777216 B
  u16* Kp = (u16*)(ws + 50331648);         // [B,H,S,D]
  u16* Vp = (u16*)(ws + 67108864);         // [B,H,D,S]      (ends 80 MB)
  u16* xb = (u16*)d_out;                   // [4096,2048] bf16, dead before final GEMM

  prep_kernel<<<dim3(69632), dim3(256), 0, stream>>>(x, cpq, cpk, cpv, cpo, xb, Wqkv, Wo, ncp, factor);
  gemm_qkv<<<dim3(24, 32), dim3(512), 0, stream>>>(xb, Wqkv, Qp, Kp, Vp);
  flash_attn<<<dim3(512), dim3(256), 0, stream>>>(Qp, Kp, Vp, At);
  gemm_bt<1><<<dim3(16, 32), dim3(256), 0, stream>>>(At, Wo, nullptr, nullptr, nullptr, out);
}

// Round 4
// 345.385 us; speedup vs baseline: 1.0452x; 1.0296x over previous
//
#include <hip/hip_runtime.h>
#include <stdint.h>

typedef unsigned short u16;
typedef __bf16 bf16x8 __attribute__((ext_vector_type(8)));
typedef float f32x4 __attribute__((ext_vector_type(4)));
typedef u16 u16x4 __attribute__((ext_vector_type(4)));

#define MFMA16(a, b, c) __builtin_amdgcn_mfma_f32_16x16x32_bf16((a), (b), (c), 0, 0, 0)

__device__ __forceinline__ u16 f2bf(float f) {
  uint32_t u = __builtin_bit_cast(uint32_t, f);
  u += 0x7FFFu + ((u >> 16) & 1u);  // RNE
  return (u16)(u >> 16);
}
__device__ __forceinline__ bf16x8 cvt8(f32x4 lo, f32x4 hi) {
  union { u16 u[8]; bf16x8 v; } r;
#pragma unroll
  for (int j = 0; j < 4; j++) { r.u[j] = f2bf(lo[j]); r.u[4 + j] = f2bf(hi[j]); }
  return r.v;
}
// async global->LDS, 16B per lane. LDS dest = wave-uniform base + lane*16.
__device__ __forceinline__ void gld_lds16(const void* g, void* l) {
  __builtin_amdgcn_global_load_lds(
      (const __attribute__((address_space(1))) uint32_t*)g,
      (__attribute__((address_space(3))) uint32_t*)l, 16, 0, 0);
}

// ---------------------------------------------------------------------------
// Fused prep: blocks [0,65536) spline-interp the 4 weight curves (n=32539
// f32 cps -> 4.2M bf16 samples each); blocks [65536,69632) convert x f32->bf16.
// ---------------------------------------------------------------------------
__global__ void prep_kernel(const float* __restrict__ x, const float* __restrict__ cpq,
                            const float* __restrict__ cpk, const float* __restrict__ cpv,
                            const float* __restrict__ cpo, u16* __restrict__ xb,
                            u16* __restrict__ Wqkv, u16* __restrict__ Wo,
                            int n, double factor) {
  int blk = blockIdx.x;
  if (blk < 65536) {
    int idx = blk * 256 + threadIdx.x;           // < 4*4194304
    int w = idx >> 22;
    int i = idx & 4194303;
    const float* cp = (w == 0) ? cpq : (w == 1) ? cpk : (w == 2) ? cpv : cpo;
    double u = (double)i * factor;               // f64: f32 too coarse here
    int i0 = (int)u;
    if (i0 > n - 2) i0 = n - 2;
    float fr = (float)(u - (double)i0);
    float f0 = cp[i0], f1 = cp[i0 + 1];
    u16 bv = f2bf(f0 + fr * (f1 - f0));
    if (w < 3) Wqkv[idx] = bv; else Wo[i] = bv;
  } else {
    size_t i = ((size_t)(blk - 65536) * 256 + threadIdx.x) * 8;
    const f32x4* p = (const f32x4*)(x + i);
    *(bf16x8*)(xb + i) = cvt8(p[0], p[1]);
  }
}

// ---------------------------------------------------------------------------
// QKV projection GEMM, round-4: LDS-bandwidth-driven retile.
// Model (validated on R0=44%, R3=37.8%, m201=62%): MfmaUtil cap =
// MFMA_cyc / LDS_cyc where LDS = (reads 8waves*(Mw+Nw)*BK*2B + writes
// (BM+BN)*BK*2B) / 256 B/cyc. Wave tile 128x96 on a 256x384 block:
// cap = 931/1210 = 77% (vs 45% for R3's 64x64 waves).
// C[M=4096, N=6144] = A[M,2048] @ B[N,2048]^T, bf16 in, f32 acc.
// BM=256 x BN=384 x BK=64, 512 threads (8 waves: wm=wave&1 -> 128-row half,
// wn=wave>>1 -> 96-col strip), acc[8][6] (192 VGPR).
// Grid dim3(16,16) = 256 blocks = EXACTLY ONE ROUND (1 block/CU, no tail).
// XCD: linear%8 = blockIdx.x%8 -> 2 B-panels (3 MB) L2-resident per XCD.
// LDS: DOUBLE-buffered As(32K)+Bs(48K) = 163840 B = the full 160 KiB.
// VGPR economy: row&7 == l16&7 (i*16, wm*128, wn*96 all =0 mod 8), so the
// XOR-swizzled LDS read addr = ONE base VGPR per operand per t-step;
// i*2048 / j*2048 / CUR*buf are ds_read immediates (max 65520/98288, in
// range). af read per-i (live 1-2), bf[6] per t-step.
// Ledger (10 loads/thread/tile, 2 buffers):
//   prologue: stage(0->b0) stage(1->b1); vmcnt(10) [t0 done]; barrier
//   body(t):  2 t-steps {bf[6] reads; per-i: af read + 6 MFMA (setprio)}
//             lgkmcnt(0); barrier  [all waves' reads RETURNED -> safe to
//             overwrite]; stage(t+2 -> buf[t&1]); vmcnt(10) [t+1 done,
//             t+2's 10 in flight -- never drained]; barrier; sched_barrier
//   tail: body(30) no stage, vmcnt(0); body(31) bare.
// Swizzle: proven R0 involution (gc = c^(r&7) on source, chunk^(t*4) on read).
// ---------------------------------------------------------------------------
__global__ __launch_bounds__(512, 2)
void gemm_qkv(const u16* __restrict__ A, const u16* __restrict__ B,
              u16* __restrict__ oQ, u16* __restrict__ oK, u16* __restrict__ oV) {
  __shared__ __align__(16) u16 As[2 * 256 * 64];   // 65536 B
  __shared__ __align__(16) u16 Bs[2 * 384 * 64];   // 98304 B
  const int tid = threadIdx.x;
  const int wave = tid >> 6, lane = tid & 63, quad = lane >> 4, l16 = lane & 15;
  const int wm = wave & 1, wn = wave >> 1;         // 2m x 4n wave grid
  const int m0 = blockIdx.y * 256, n0 = blockIdx.x * 384;

  // stage global offsets (32-bit: A=16MB, B=25MB), R0-proven inverse swizzle
  uint32_t aoffg[4], boffg[6];
#pragma unroll
  for (int u = 0; u < 4; u++) {
    int s = u * 512 + tid, r = s >> 3, c = s & 7, gc = c ^ (r & 7);
    aoffg[u] = (uint32_t)(m0 + r) * 4096u + gc * 16;
  }
#pragma unroll
  for (int u = 0; u < 6; u++) {
    int s = u * 512 + tid, r = s >> 3, c = s & 7, gc = c ^ (r & 7);
    boffg[u] = (uint32_t)(n0 + r) * 4096u + gc * 16;
  }

  // ds_read swizzled bases; i/j/CUR offsets are immediates
  const int swz = (quad ^ (l16 & 7)) * 16;
  const int baseA0 = (wm * 128 + l16) * 128 + swz;
  const int baseA1 = baseA0 ^ 64;                  // t-step 1: chunk ^ 4
  const int baseB0 = (wn * 96 + l16) * 128 + swz;
  const int baseB1 = baseB0 ^ 64;

  const char* Ab = (const char*)A;
  const char* Bb = (const char*)B;
  char* AsB = (char*)As;
  char* BsB = (char*)Bs;

  f32x4 acc[8][6];
  const f32x4 fz = {0.f, 0.f, 0.f, 0.f};
#pragma unroll
  for (int i = 0; i < 8; i++)
#pragma unroll
    for (int j = 0; j < 6; j++) acc[i][j] = fz;

#define QKV_STAGE(TT, NX)                                                     \
  do {                                                                        \
    uint32_t kb = (uint32_t)(TT) * 128u;                                      \
    _Pragma("unroll") for (int u = 0; u < 4; u++)                             \
      gld_lds16(Ab + (size_t)(aoffg[u] + kb),                                 \
                AsB + (NX) * 32768 + u * 8192 + tid * 16);                    \
    _Pragma("unroll") for (int u = 0; u < 6; u++)                             \
      gld_lds16(Bb + (size_t)(boffg[u] + kb),                                 \
                BsB + (NX) * 49152 + u * 8192 + tid * 16);                    \
  } while (0)

#define QKV_TSTEP(CUR, BA, BB)                                                \
  do {                                                                        \
    bf16x8 bfv[6];                                                            \
    _Pragma("unroll") for (int j = 0; j < 6; j++)                             \
      bfv[j] = *(const bf16x8*)(BsB + (CUR) * 49152 + (BB) + j * 2048);       \
    _Pragma("unroll") for (int i = 0; i < 8; i++) {                           \
      bf16x8 afv = *(const bf16x8*)(AsB + (CUR) * 32768 + (BA) + i * 2048);   \
      __builtin_amdgcn_s_setprio(1);                                          \
      _Pragma("unroll") for (int j = 0; j < 6; j++)                           \
        acc[i][j] = MFMA16(afv, bfv[j], acc[i][j]);                           \
      __builtin_amdgcn_s_setprio(0);                                          \
    }                                                                         \
  } while (0)

// STG: stage tile T+2 into buf[T&1]. WM: 10=vmcnt(10), 0=vmcnt(0), -1=none
#define QKV_BODY(T, CUR, STG, WM)                                             \
  do {                                                                        \
    QKV_TSTEP(CUR, baseA0, baseB0);                                           \
    QKV_TSTEP(CUR, baseA1, baseB1);                                           \
    if (STG) {                                                                \
      asm volatile("s_waitcnt lgkmcnt(0)" ::: "memory");                      \
      __builtin_amdgcn_s_barrier();                                           \
      __builtin_amdgcn_sched_barrier(0);                                      \
      QKV_STAGE((T) + 2, CUR);                                                \
    }                                                                         \
    if ((WM) == 10) asm volatile("s_waitcnt vmcnt(10)" ::: "memory");         \
    else if ((WM) == 0) asm volatile("s_waitcnt vmcnt(0)" ::: "memory");      \
    if ((WM) >= 0) {                                                          \
      __builtin_amdgcn_s_barrier();                                           \
      __builtin_amdgcn_sched_barrier(0);                                      \
    }                                                                         \
  } while (0)

  // prologue: tiles 0,1 -> buf 0,1; wait tile0 (tile1's 10 stay in flight)
  QKV_STAGE(0, 0);
  QKV_STAGE(1, 1);
  asm volatile("s_waitcnt vmcnt(10)" ::: "memory");
  __builtin_amdgcn_s_barrier();
  __builtin_amdgcn_sched_barrier(0);

  for (int t = 0; t < 30; t += 2) {   // tiles 0..29; stages 2..31
    QKV_BODY(t, 0, true, 10);
    QKV_BODY(t + 1, 1, true, 10);
  }
  QKV_BODY(30, 0, false, 0);          // drain tile31's loads
  QKV_BODY(31, 1, false, -1);
#undef QKV_BODY
#undef QKV_TSTEP
#undef QKV_STAGE

  // epilogue: C frag layout col=lane&15 (n), row=quad*4+reg (m). Verified R0.
  const float qscale = 0.08838834764831845f;  // folded into Q
#pragma unroll
  for (int j = 0; j < 6; j++) {
    int nb = n0 + wn * 96 + j * 16;
    int sel = nb >> 11;                      // 0=Q 1=K 2=V (per j)
    int h = (nb >> 7) & 15;
    int d = (nb & 127) + l16;
#pragma unroll
    for (int i = 0; i < 8; i++) {
      int mrow = m0 + wm * 128 + i * 16 + quad * 4;
      int bq = mrow >> 11, srow = mrow & 2047;
      if (sel == 2) {
        u16x4 pk = {f2bf(acc[i][j][0]), f2bf(acc[i][j][1]),
                    f2bf(acc[i][j][2]), f2bf(acc[i][j][3])};
        *(u16x4*)&oV[(size_t)(((bq << 4) + h) * 128 + d) * 2048 + srow] = pk;
      } else if (sel == 0) {
        int base = ((bq << 4) + h) * 2048;
#pragma unroll
        for (int r = 0; r < 4; r++)
          oQ[(size_t)(base + srow + r) * 128 + d] = f2bf(acc[i][j][r] * qscale);
      } else {
        int base = ((bq << 4) + h) * 2048;
#pragma unroll
        for (int r = 0; r < 4; r++)
          oK[(size_t)(base + srow + r) * 128 + d] = f2bf(acc[i][j][r]);
      }
    }
  }
}

// ---------------------------------------------------------------------------
// C[M,N] = A[M,2048] @ B[N,2048]^T, bf16 in, f32 acc. 128x128 tile, BK=64.
// Proven 2-barrier kernel, used for the output projection (MODE 1).
// ---------------------------------------------------------------------------
template <int MODE>
__global__ __launch_bounds__(256, 2)
void gemm_bt(const u16* __restrict__ A, const u16* __restrict__ B,
             u16* __restrict__ oQ, u16* __restrict__ oK, u16* __restrict__ oV,
             float* __restrict__ oC) {
  constexpr int KD = 2048;
  __shared__ __align__(16) u16 As[128 * 64];
  __shared__ __align__(16) u16 Bs[128 * 64];
  const int tid = threadIdx.x;
  const int wave = tid >> 6, lane = tid & 63, quad = lane >> 4, l16 = lane & 15;
  const int wm = wave & 1, wn = wave >> 1;
  const int m0 = blockIdx.y * 128, n0 = blockIdx.x * 128;

  size_t aoff[4], boff[4];
  int lslot[4];
#pragma unroll
  for (int b = 0; b < 4; b++) {
    int s = wave * 256 + b * 64 + lane;  // chunk slot 0..1023 (16B chunks)
    int r = s >> 3, c = s & 7, gc = c ^ (r & 7);
    lslot[b] = s * 16;
    aoff[b] = (size_t)(m0 + r) * (KD * 2) + gc * 16;
    boff[b] = (size_t)(n0 + r) * (KD * 2) + gc * 16;
  }
  const char* Ab = (const char*)A;
  const char* Bb = (const char*)B;
  char* AsB = (char*)As;
  char* BsB = (char*)Bs;

  f32x4 acc[4][4];
  const f32x4 fz = {0.f, 0.f, 0.f, 0.f};
#pragma unroll
  for (int i = 0; i < 4; i++)
#pragma unroll
    for (int j = 0; j < 4; j++) acc[i][j] = fz;

  for (int kt = 0; kt < KD / 64; ++kt) {
    if (kt) __syncthreads();
#pragma unroll
    for (int b = 0; b < 4; b++) {
      gld_lds16(Ab + aoff[b], AsB + lslot[b]);
      gld_lds16(Bb + boff[b], BsB + lslot[b]);
      aoff[b] += 128;
      boff[b] += 128;
    }
    __syncthreads();
#pragma unroll
    for (int t = 0; t < 2; t++) {
      bf16x8 af[4], bfb[4];
#pragma unroll
      for (int i = 0; i < 4; i++) {
        int row = wm * 64 + i * 16 + l16;
        int ch = (t * 4 + quad) ^ (row & 7);
        af[i] = *(const bf16x8*)(AsB + row * 128 + ch * 16);
      }
#pragma unroll
      for (int j = 0; j < 4; j++) {
        int row = wn * 64 + j * 16 + l16;
        int ch = (t * 4 + quad) ^ (row & 7);
        bfb[j] = *(const bf16x8*)(BsB + row * 128 + ch * 16);
      }
#pragma unroll
      for (int i = 0; i < 4; i++)
#pragma unroll
        for (int j = 0; j < 4; j++) acc[i][j] = MFMA16(af[i], bfb[j], acc[i][j]);
    }
  }

  if (MODE == 0) {
    const float qscale = 0.08838834764831845f;
#pragma unroll
    for (int j = 0; j < 4; j++) {
      int nb = n0 + wn * 64 + j * 16;
      int sel = nb >> 11;
      int h = (nb >> 7) & 15;
      int d = (nb & 127) + l16;
#pragma unroll
      for (int i = 0; i < 4; i++) {
        int mrow = m0 + wm * 64 + i * 16 + quad * 4;
        int bq = mrow >> 11, srow = mrow & 2047;
        if (sel == 2) {
          u16x4 pk = {f2bf(acc[i][j][0]), f2bf(acc[i][j][1]),
                      f2bf(acc[i][j][2]), f2bf(acc[i][j][3])};
          *(u16x4*)&oV[(size_t)(((bq << 4) + h) * 128 + d) * 2048 + srow] = pk;
        } else if (sel == 0) {
          int base = ((bq << 4) + h) * 2048;
#pragma unroll
          for (int r = 0; r < 4; r++)
            oQ[(size_t)(base + srow + r) * 128 + d] = f2bf(acc[i][j][r] * qscale);
        } else {
          int base = ((bq << 4) + h) * 2048;
#pragma unroll
          for (int r = 0; r < 4; r++)
            oK[(size_t)(base + srow + r) * 128 + d] = f2bf(acc[i][j][r]);
        }
      }
    }
  } else {
#pragma unroll
    for (int j = 0; j < 4; j++) {
      int col = n0 + wn * 64 + j * 16 + l16;
#pragma unroll
      for (int i = 0; i < 4; i++) {
        int mrow = m0 + wm * 64 + i * 16 + quad * 4;
#pragma unroll
        for (int r = 0; r < 4; r++) oC[(size_t)(mrow + r) * 2048 + col] = acc[i][j][r];
      }
    }
  }
}

// ---------------------------------------------------------------------------
// Causal flash attention, Bc=64, max-free softmax, TRANSPOSED QK (unchanged).
// ---------------------------------------------------------------------------
__global__ __launch_bounds__(256, 2)
void flash_attn(const u16* __restrict__ Q, const u16* __restrict__ Kg,
                const u16* __restrict__ Vt, u16* __restrict__ attn) {
  __shared__ __align__(16) u16 Ks[64 * 128];
  __shared__ __align__(16) u16 Vs[128 * 64];
  __shared__ __align__(16) u16 Ps[128 * 72];
  const int tid = threadIdx.x;
  const int wave = tid >> 6, lane = tid & 63, quad = lane >> 4, l16 = lane & 15;
  const int L = blockIdx.x;
  const int bh = L & 31;
  const int qi = (L >> 5) & 7;
  const int qt = (L >= 256) ? (15 - qi) : qi;
  const int q0 = qt * 128;
  const u16* Qb = Q + (size_t)bh * 2048 * 128;
  const u16* Kb = Kg + (size_t)bh * 2048 * 128;
  const u16* Vb = Vt + (size_t)bh * 128 * 2048;

  bf16x8 qf[2][4];
#pragma unroll
  for (int i = 0; i < 2; i++) {
    int row = q0 + wave * 32 + i * 16 + l16;
#pragma unroll
    for (int t = 0; t < 4; t++)
      qf[i][t] = *(const bf16x8*)(Qb + (size_t)row * 128 + t * 32 + quad * 8);
  }

  f32x4 o_acc[2][8];
  const f32x4 fz = {0.f, 0.f, 0.f, 0.f};
#pragma unroll
  for (int i = 0; i < 2; i++)
#pragma unroll
    for (int j = 0; j < 8; j++) o_acc[i][j] = fz;
  float l_i[2] = {0.f, 0.f};

  int koff[4], voff[4], lslot[4];
#pragma unroll
  for (int b = 0; b < 4; b++) {
    int s = wave * 256 + b * 64 + lane;  // 0..1023
    lslot[b] = s * 16;
    {
      int r = s >> 4, c = s & 15;
      int gc = (c & 8) | ((c & 7) ^ (r & 7));
      koff[b] = r * 256 + gc * 16;
    }
    {
      int r = s >> 3, c = s & 7;
      int gc = c ^ (r & 7);
      voff[b] = r * 4096 + gc * 16;
    }
  }
  const char* KbB = (const char*)Kb;
  const char* VbB = (const char*)Vb;
  char* KsB = (char*)Ks;
  char* VsB = (char*)Vs;

  const int ktmax = 2 * qt + 1;

  for (int kt = 0; kt <= ktmax; ++kt) {
    const int k0 = kt * 64;
    if (kt) __syncthreads();
#pragma unroll
    for (int b = 0; b < 4; b++) {
      gld_lds16(KbB + (size_t)k0 * 256 + koff[b], KsB + lslot[b]);
      gld_lds16(VbB + (size_t)k0 * 2 + voff[b], VsB + lslot[b]);
    }
    __syncthreads();

    f32x4 st[2][4];
#pragma unroll
    for (int i = 0; i < 2; i++)
#pragma unroll
      for (int j = 0; j < 4; j++) st[i][j] = fz;
#pragma unroll
    for (int j = 0; j < 4; j++) {
      int rowk = j * 16 + l16;
#pragma unroll
      for (int t = 0; t < 4; t++) {
        int cc = t * 4 + quad;
        int ch = (cc & 8) | ((cc & 7) ^ (rowk & 7));
        bf16x8 kfr = *(const bf16x8*)(KsB + rowk * 256 + ch * 16);
        st[0][j] = MFMA16(kfr, qf[0][t], st[0][j]);
        st[1][j] = MFMA16(kfr, qf[1][t], st[1][j]);
      }
    }

    const bool do_mask = (kt >= 2 * qt);
#pragma unroll
    for (int i = 0; i < 2; i++) {
      const int qg = q0 + wave * 32 + i * 16 + l16;
      float lacc = 0.f;
#pragma unroll
      for (int j = 0; j < 4; j++) {
        float p[4];
#pragma unroll
        for (int r = 0; r < 4; r++) {
          float v = st[i][j][r];
          if (do_mask && (k0 + j * 16 + quad * 4 + r > qg)) v = -1e30f;
          p[r] = __expf(v);
        }
        lacc += (p[0] + p[1]) + (p[2] + p[3]);
        u16x4 pk = {f2bf(p[0]), f2bf(p[1]), f2bf(p[2]), f2bf(p[3])};
        *(u16x4*)&Ps[(wave * 32 + i * 16 + l16) * 72 + j * 16 + quad * 4] = pk;
      }
      l_i[i] += lacc;
    }

#pragma unroll
    for (int t = 0; t < 2; t++) {
      bf16x8 af0 = *(const bf16x8*)((char*)Ps + (wave * 32 + l16) * 144 + (t * 32 + quad * 8) * 2);
      bf16x8 af1 = *(const bf16x8*)((char*)Ps + (wave * 32 + 16 + l16) * 144 + (t * 32 + quad * 8) * 2);
#pragma unroll
      for (int j = 0; j < 8; j++) {
        int vrow = j * 16 + l16;
        int ch = (t * 4 + quad) ^ (vrow & 7);
        bf16x8 bfr = *(const bf16x8*)(VsB + vrow * 128 + ch * 16);
        o_acc[0][j] = MFMA16(af0, bfr, o_acc[0][j]);
        o_acc[1][j] = MFMA16(af1, bfr, o_acc[1][j]);
      }
    }
  }

  const int bb = bh >> 4, h = bh & 15;
#pragma unroll
  for (int i = 0; i < 2; i++) {
    float rs = l_i[i];
    rs += __shfl_xor(rs, 16);
    rs += __shfl_xor(rs, 32);
    float inv = 1.f / rs;
#pragma unroll
    for (int r = 0; r < 4; r++) {
      float invr = __shfl(inv, (lane & 48) | (quad * 4 + r), 64);
      int srow = q0 + wave * 32 + i * 16 + quad * 4 + r;
      size_t base = ((size_t)(bb * 2048 + srow)) * 2048 + h * 128;
#pragma unroll
      for (int j = 0; j < 8; j++) attn[base + j * 16 + l16] = f2bf(o_acc[i][j][r] * invr);
    }
  }
}

// ---------------------------------------------------------------------------
extern "C" void kernel_launch(void* const* d_in, const int* in_sizes, int n_in,
                              void* d_out, int out_size, void* d_ws, size_t ws_size,
                              hipStream_t stream) {
  (void)n_in; (void)out_size; (void)ws_size;
  const float* x = (const float*)d_in[0];     // [2,2048,2048] f32
  const float* cpq = (const float*)d_in[1];
  const float* cpk = (const float*)d_in[2];
  const float* cpv = (const float*)d_in[3];
  const float* cpo = (const float*)d_in[4];
  // d_in[5] = attention_mask: causal, applied analytically -> unused
  float* out = (float*)d_out;
  const int ncp = in_sizes[1];                // 32539
  const double factor = (double)(ncp - 1) / 4194303.0;

  char* ws = (char*)d_ws;
  u16* Wqkv = (u16*)(ws);                  // 6144*2048 bf16 = 25165824 B
  u16* At   = (u16*)(ws);                  // [B,S,H*D] 16MB, reuses dead Wqkv
  u16* Wo = (u16*)(ws + 25165824);         // 2048*2048 bf16 =  8388608 B
  u16* Qp = (u16*)(ws + 33554432);         // [B,H,S,D] bf16 = 16777216 B
  u16* Kp = (u16*)(ws + 50331648);         // [B,H,S,D]
  u16* Vp = (u16*)(ws + 67108864);         // [B,H,D,S]      (ends 80 MB)
  u16* xb = (u16*)d_out;                   // [4096,2048] bf16, dead before final GEMM

  prep_kernel<<<dim3(69632), dim3(256), 0, stream>>>(x, cpq, cpk, cpv, cpo, xb, Wqkv, Wo, ncp, factor);
  gemm_qkv<<<dim3(16, 16), dim3(512), 0, stream>>>(xb, Wqkv, Qp, Kp, Vp);
  flash_attn<<<dim3(512), dim3(256), 0, stream>>>(Qp, Kp, Vp, At);
  gemm_bt<1><<<dim3(16, 32), dim3(256), 0, stream>>>(At, Wo, nullptr, nullptr, nullptr, out);
}